// Round 7
// baseline (728.060 us; speedup 1.0000x reference)
//
#include <hip/hip_runtime.h>

#define NT 16384
#define DM 4096
#define NE 64
#define TOPK 8
#define EPW 8              // experts per wave -> 8 named accumulators only
#define NEGINF (-3.402823466e38f)

#define FOR_8(A) A(0) A(1) A(2) A(3) A(4) A(5) A(6) A(7)

// dot of the 16-float x window with expert e's 16-float W window, two-level
// accumulation (window partial s, then acc += s) to match numpy-level error.
#define DOT_E(e) { \
  const float* _w = wb + (size_t)(e) * DM + k; \
  const float4 w0 = *(const float4*)(_w); \
  const float4 w1 = *(const float4*)(_w + 4); \
  const float4 w2 = *(const float4*)(_w + 8); \
  const float4 w3 = *(const float4*)(_w + 12); \
  float s; \
  s = xv0.x * w0.x;        s = fmaf(xv0.y, w0.y, s); \
  s = fmaf(xv0.z, w0.z, s); s = fmaf(xv0.w, w0.w, s); \
  s = fmaf(xv1.x, w1.x, s); s = fmaf(xv1.y, w1.y, s); \
  s = fmaf(xv1.z, w1.z, s); s = fmaf(xv1.w, w1.w, s); \
  s = fmaf(xv2.x, w2.x, s); s = fmaf(xv2.y, w2.y, s); \
  s = fmaf(xv2.z, w2.z, s); s = fmaf(xv2.w, w2.w, s); \
  s = fmaf(xv3.x, w3.x, s); s = fmaf(xv3.y, w3.y, s); \
  s = fmaf(xv3.z, w3.z, s); s = fmaf(xv3.w, w3.w, s); \
  acc##e += s; }

// stable branchless bubble-insert of (val,idx) into descending top-8
// (v0..v7 / i0..i7). Ties: strict > keeps the earlier (lower) index on top,
// matching jax.lax.top_k tie-breaking.
#define INS1(val, idx) { \
  float cv = (val); int ci = (idx); \
  { const bool b = cv > v0; const float tv = v0; const int ti = i0; \
    v0 = b ? cv : v0; i0 = b ? ci : i0; cv = b ? tv : cv; ci = b ? ti : ci; } \
  { const bool b = cv > v1; const float tv = v1; const int ti = i1; \
    v1 = b ? cv : v1; i1 = b ? ci : i1; cv = b ? tv : cv; ci = b ? ti : ci; } \
  { const bool b = cv > v2; const float tv = v2; const int ti = i2; \
    v2 = b ? cv : v2; i2 = b ? ci : i2; cv = b ? tv : cv; ci = b ? ti : ci; } \
  { const bool b = cv > v3; const float tv = v3; const int ti = i3; \
    v3 = b ? cv : v3; i3 = b ? ci : i3; cv = b ? tv : cv; ci = b ? ti : ci; } \
  { const bool b = cv > v4; const float tv = v4; const int ti = i4; \
    v4 = b ? cv : v4; i4 = b ? ci : i4; cv = b ? tv : cv; ci = b ? ti : ci; } \
  { const bool b = cv > v5; const float tv = v5; const int ti = i5; \
    v5 = b ? cv : v5; i5 = b ? ci : i5; cv = b ? tv : cv; ci = b ? ti : ci; } \
  { const bool b = cv > v6; const float tv = v6; const int ti = i6; \
    v6 = b ? cv : v6; i6 = b ? ci : i6; cv = b ? tv : cv; ci = b ? ti : ci; } \
  { const bool b = cv > v7; \
    v7 = b ? cv : v7; i7 = b ? ci : i7; } }

__global__ __launch_bounds__(512, 2) void gate_kernel(
    const float* __restrict__ x,
    const float* __restrict__ W,
    int* __restrict__ out) {

  const int lane = threadIdx.x & 63;
  const int wid  = (int)(threadIdx.x >> 6);   // expert-group 0..7
  const int tok  = blockIdx.x * 64 + lane;
  const int ebase = wid * EPW;

#define DECL_ACC(e) float acc##e = 0.f;
  FOR_8(DECL_ACC)

  const float* xr = x + (size_t)tok * DM;
  const float* wb = W + (size_t)ebase * DM;

  for (int k = 0; k < DM; k += 16) {
    const float4 xv0 = *(const float4*)(xr + k);
    const float4 xv1 = *(const float4*)(xr + k + 4);
    const float4 xv2 = *(const float4*)(xr + k + 8);
    const float4 xv3 = *(const float4*)(xr + k + 12);
    FOR_8(DOT_E)
  }

  // ---- gather the 64 logits per token into LDS ----
  __shared__ float red[64][68]; // row stride 68 floats = 272 B (16B-aligned)
  *(float4*)&red[lane][ebase]     = make_float4(acc0, acc1, acc2, acc3);
  *(float4*)&red[lane][ebase + 4] = make_float4(acc4, acc5, acc6, acc7);
  __syncthreads();

  // ---- wave 0: lane t = token t, stable insertion top-8 over 64 logits ----
  if (wid == 0) {
    float v0 = NEGINF, v1 = NEGINF, v2 = NEGINF, v3 = NEGINF;
    float v4 = NEGINF, v5 = NEGINF, v6 = NEGINF, v7 = NEGINF;
    int i0 = 0, i1 = 0, i2 = 0, i3 = 0, i4 = 0, i5 = 0, i6 = 0, i7 = 0;
#pragma unroll
    for (int eq = 0; eq < 16; ++eq) {
      const float4 c = *(const float4*)&red[lane][eq * 4];
      INS1(c.x, eq * 4 + 0)
      INS1(c.y, eq * 4 + 1)
      INS1(c.z, eq * 4 + 2)
      INS1(c.w, eq * 4 + 3)
    }
    int4* op = (int4*)(out + (size_t)tok * TOPK);
    op[0] = make_int4(i0, i1, i2, i3);
    op[1] = make_int4(i4, i5, i6, i7);
  }
}

extern "C" void kernel_launch(void* const* d_in, const int* in_sizes, int n_in,
                              void* d_out, int out_size, void* d_ws, size_t ws_size,
                              hipStream_t stream) {
  const float* x = (const float*)d_in[0];
  const float* W = (const float*)d_in[1];
  int* out = (int*)d_out;
  (void)in_sizes; (void)n_in; (void)out_size; (void)d_ws; (void)ws_size;

  dim3 grid(NT / 64);   // 256 blocks: 64 tokens each
  dim3 block(512);      // 8 waves: 8 expert-groups sharing the x tile via L1/L2
  hipLaunchKernelGGL(gate_kernel, grid, block, 0, stream, x, W, out);
}